// Round 13
// baseline (398.330 us; speedup 1.0000x reference)
//
#include <hip/hip_runtime.h>
#include <cstdint>

typedef unsigned int u32;
typedef unsigned long long u64;

#define NCLS 21
#define TOPK 200
#define MAXP 8732
#define CAND 384

// Scores: XLA:GPU(gfx950) softmax emulation — exp(x) = v_exp_f32(x*log2e)
// (hardware exp2 fast path, same chip => same bits), butterfly-tree sum.
// Everything else: stepwise IEEE f32, no fusion.
#pragma clang fp contract(off)

__device__ __forceinline__ float tri_expf(float x) {
  float t = __fmul_rn(x, 1.4426950408889634f);   // f32 log2e = 0x3FB8AA3B
  return __builtin_amdgcn_exp2f(t);               // v_exp_f32
}

// Padded-to-32 butterfly tree sum (offsets 16,8,4,2,1); lanes 21..31 are +0.0
// (exact identity), reproducing the warp-reduce association.
__device__ __forceinline__ float butterfly_sum21(const float* e) {
  float v[32];
#pragma unroll
  for (int k = 0; k < NCLS; ++k) v[k] = e[k];
#pragma unroll
  for (int k = NCLS; k < 32; ++k) v[k] = 0.0f;
  float a[16], b[8], c4[4], d2[2];
#pragma unroll
  for (int i = 0; i < 16; ++i) a[i] = __fadd_rn(v[i], v[i + 16]);
#pragma unroll
  for (int i = 0; i < 8; ++i) b[i] = __fadd_rn(a[i], a[i + 8]);
#pragma unroll
  for (int i = 0; i < 4; ++i) c4[i] = __fadd_rn(b[i], b[i + 4]);
#pragma unroll
  for (int i = 0; i < 2; ++i) d2[i] = __fadd_rn(c4[i], c4[i + 2]);
  return __fadd_rn(d2[0], d2[1]);
}

// Softmax row: exact max, e[k] = exp2-path exp(x-mx), butterfly sum.
__device__ __forceinline__ void softmax_row(const float* __restrict__ row,
                                            float* e, float& mx, float& S) {
  float xs[NCLS];
#pragma unroll
  for (int k = 0; k < NCLS; ++k) xs[k] = row[k];
  mx = xs[0];
#pragma unroll
  for (int k = 1; k < NCLS; ++k) mx = fmaxf(mx, xs[k]);
#pragma unroll
  for (int k = 0; k < NCLS; ++k) e[k] = tri_expf(__fsub_rn(xs[k], mx));
  S = butterfly_sum21(e);
}

// TIER 2: write transposed f32 probs. TIER 1: write (mx, S) per row.
template<int TIER>
__global__ __launch_bounds__(256) void prep_k(const float* __restrict__ conf,
                                              float2* __restrict__ denoms,
                                              float* __restrict__ probs_t,
                                              int B, int P) {
  int gid = blockIdx.x * 256 + threadIdx.x;
  if (gid >= B * P) return;
  int b = gid / P, p = gid - b * P;
  float e[NCLS], mx, S;
  softmax_row(conf + (size_t)gid * NCLS, e, mx, S);
  if (TIER == 2) {
#pragma unroll
    for (int c = 1; c < NCLS; ++c)
      probs_t[((size_t)b * (NCLS - 1) + (c - 1)) * P + p] = __fdiv_rn(e[c], S);
  } else {
    denoms[gid] = make_float2(mx, S);
  }
}

template<int TIER>
__global__ __launch_bounds__(256) void ssd_k(
    const float* __restrict__ loc, const float* __restrict__ conf,
    const float* __restrict__ priors, const float2* __restrict__ denoms,
    const float* __restrict__ probs_t, float* __restrict__ out, int B, int P) {
  __shared__ __align__(16) u32 sc[MAXP];   // f32 prob bits per prior
  __shared__ u64 ckey[CAND];               // (bits<<32) | (0xFFFFFFFF - p)
  __shared__ u32 hist[256];
  __shared__ int srt[TOPK];                // rank -> candidate slot
  __shared__ float bx[TOPK][4];
  __shared__ float vals[TOPK];
  __shared__ __align__(16) float st[TOPK * 5];
  __shared__ u32 s_prefix;
  __shared__ int s_K, s_cnt, s_nv;
  __shared__ u64 s_kw[4];

  const int tid = threadIdx.x;
  const int task = blockIdx.x;             // b*20 + (class-1)
  const int b = task / (NCLS - 1), cm1 = task - b * (NCLS - 1);
  const int c = cm1 + 1;

  // zero the background-class rows of this image
  if (cm1 == 0) {
    float* bg = out + (size_t)b * (NCLS * TOPK * 5);
    for (int i = tid; i < TOPK * 5; i += 256) bg[i] = 0.0f;
  }

  // ---- Phase A: f32 prob bits (exact score-pipeline values) into LDS
  if (TIER == 2) {
    const float* base = probs_t + (size_t)task * P;
    for (int p = tid; p < P; p += 256) sc[p] = __float_as_uint(base[p]);
  } else if (TIER == 1) {
    for (int p = tid; p < P; p += 256) {
      float2 d = denoms[(size_t)b * P + p];
      float cv = conf[((size_t)b * P + p) * NCLS + c];
      float v = __fdiv_rn(tri_expf(__fsub_rn(cv, d.x)), d.y);
      sc[p] = __float_as_uint(v);
    }
  } else {
    for (int p = tid; p < P; p += 256) {
      float e[NCLS], mx, S;
      softmax_row(conf + ((size_t)b * P + p) * NCLS, e, mx, S);
      sc[p] = __float_as_uint(__fdiv_rn(e[c], S));
    }
  }
  if (tid == 0) s_cnt = 0;
  __syncthreads();

  // ---- Phase B: radix-select the rank-200 bits threshold T (exact, with ties)
  u32 prefix = 0; int K = TOPK;
  for (int pass = 0; pass < 4; ++pass) {
    int shift = 24 - 8 * pass;
    u32 known = (pass == 0) ? 0u : (0xFFFFFFFFu << (32 - 8 * pass));
    hist[tid] = 0;
    __syncthreads();
    for (int p = tid; p < P; p += 256) {
      u32 v = sc[p];
      if ((v & known) == prefix) atomicAdd(&hist[(v >> shift) & 0xFFu], 1u);
    }
    __syncthreads();
    for (int off = 1; off < 256; off <<= 1) {   // suffix sum
      u32 add = (tid + off < 256) ? hist[tid + off] : 0u;
      __syncthreads();
      hist[tid] += add;
      __syncthreads();
    }
    u32 ge = hist[tid];
    u32 gt = (tid == 255) ? 0u : hist[tid + 1];
    if (ge >= (u32)K && gt < (u32)K) { s_prefix = prefix | ((u32)tid << shift); s_K = K - (int)gt; }
    __syncthreads();
    prefix = s_prefix; K = s_K;
    __syncthreads();
  }
  const u32 T = prefix;

  // ---- Phase C: compact candidates (bits >= T); key: desc bits, asc index
  for (int p = tid; p < P; p += 256) {
    u32 v = sc[p];
    if (v >= T) {
      int slot = atomicAdd(&s_cnt, 1);
      if (slot < CAND)
        ckey[slot] = ((u64)v << 32) | (u64)(0xFFFFFFFFu - (u32)p);
    }
  }
  __syncthreads();
  int cnt = s_cnt; if (cnt > CAND) cnt = CAND;

  // ---- Phase D: exact rank by counting (keys unique; cnt in [200, ~210])
  for (int i = tid; i < cnt; i += 256) {
    u64 k = ckey[i]; int r = 0;
    for (int j = 0; j < cnt; ++j) r += (ckey[j] > k) ? 1 : 0;
    if (r < TOPK) srt[r] = i;
  }
  if (tid == 0) s_nv = TOPK;
  __syncthreads();

  // ---- Phase E: gather + stepwise-f32 decode (ocml expf; reference op order)
  if (tid < TOPK) {
    u64 key = ckey[srt[tid]];
    float v = __uint_as_float((u32)(key >> 32));
    int p = (int)(0xFFFFFFFFu - (u32)(key & 0xFFFFFFFFull));
    float4 lp = ((const float4*)loc)[(size_t)b * P + p];
    float4 pr = ((const float4*)priors)[p];
    float tx = __fmul_rn(__fmul_rn(lp.x, 0.1f), pr.z);   // (loc*VAR0)*prior_wh
    float ty = __fmul_rn(__fmul_rn(lp.y, 0.1f), pr.w);
    float cx = __fadd_rn(pr.x, tx);
    float cy = __fadd_rn(pr.y, ty);
    float w = __fmul_rn(pr.z, expf(__fmul_rn(lp.z, 0.2f)));
    float h = __fmul_rn(pr.w, expf(__fmul_rn(lp.w, 0.2f)));
    float hw = __fmul_rn(w, 0.5f), hh = __fmul_rn(h, 0.5f);
    bx[tid][0] = __fsub_rn(cx, hw);
    bx[tid][1] = __fsub_rn(cy, hh);
    bx[tid][2] = __fadd_rn(cx, hw);
    bx[tid][3] = __fadd_rn(cy, hh);
    vals[tid] = v;
    if (!(v > 0.01f)) atomicMin(&s_nv, tid);
  }
  __syncthreads();

  // ---- Phase G: greedy NMS on wave 0, stepwise f32 (exact ref IoU formula)
  if (tid < 64) {
    int lane = tid;
    float jx1[4], jy1[4], jx2[4], jy2[4], aj[4];
#pragma unroll
    for (int s = 0; s < 4; ++s) {
      int j = s * 64 + lane;
      if (j < TOPK) { jx1[s]=bx[j][0]; jy1[s]=bx[j][1]; jx2[s]=bx[j][2]; jy2[s]=bx[j][3]; }
      else { jx1[s]=0.f; jy1[s]=0.f; jx2[s]=0.f; jy2[s]=0.f; }
      aj[s] = __fmul_rn(__fsub_rn(jx2[s], jx1[s]), __fsub_rn(jy2[s], jy1[s]));
    }
    u32 keepn = 0;
    int n = s_nv;
    for (int i = 0; i < n; ++i) {
      float ix1 = bx[i][0], iy1 = bx[i][1], ix2 = bx[i][2], iy2 = bx[i][3];
      float ai = __fmul_rn(__fsub_rn(ix2, ix1), __fsub_rn(iy2, iy1));
      bool sup = false;
#pragma unroll
      for (int s = 0; s < 4; ++s) {
        float ww = fmaxf(__fsub_rn(fminf(ix2, jx2[s]), fmaxf(ix1, jx1[s])), 0.0f);
        float hh = fmaxf(__fsub_rn(fminf(iy2, jy2[s]), fmaxf(iy1, jy1[s])), 0.0f);
        float inter = __fmul_rn(ww, hh);
        float den = __fsub_rn(__fadd_rn(ai, aj[s]), inter);
        float iou = __fdiv_rn(inter, den);
        if (((keepn >> s) & 1u) && (iou > 0.45f)) sup = true;
      }
      if (!__any((int)sup)) { if (lane == (i & 63)) keepn |= 1u << (i >> 6); }
    }
    u64 w0 = __ballot((int)(keepn & 1u));
    u64 w1 = __ballot((int)((keepn >> 1) & 1u));
    u64 w2 = __ballot((int)((keepn >> 2) & 1u));
    u64 w3 = __ballot((int)((keepn >> 3) & 1u));
    if (lane == 0) { s_kw[0]=w0; s_kw[1]=w1; s_kw[2]=w2; s_kw[3]=w3; }
  }
  __syncthreads();

  // ---- Phase H: compact kept rows to front, zeros elsewhere; coalesced store
  for (int i = tid; i < TOPK * 5; i += 256) st[i] = 0.0f;
  __syncthreads();
  if (tid < TOPK) {
    int w = tid >> 6, bit = tid & 63;
    u64 kw = s_kw[w];
    if ((kw >> bit) & 1ull) {
      int pos = (int)__popcll(kw & ((1ull << bit) - 1ull));
      for (int w2 = 0; w2 < w; ++w2) pos += (int)__popcll(s_kw[w2]);
      st[pos*5+0] = vals[tid];
      st[pos*5+1] = bx[tid][0];
      st[pos*5+2] = bx[tid][1];
      st[pos*5+3] = bx[tid][2];
      st[pos*5+4] = bx[tid][3];
    }
  }
  __syncthreads();
  float* op = out + (size_t)(b * NCLS + 1 + cm1) * (TOPK * 5);
  if (tid < TOPK * 5 / 4) ((float4*)op)[tid] = ((const float4*)st)[tid];
}

extern "C" void kernel_launch(void* const* d_in, const int* in_sizes, int n_in,
                              void* d_out, int out_size, void* d_ws, size_t ws_size,
                              hipStream_t stream) {
  const float* loc    = (const float*)d_in[0];
  const float* conf   = (const float*)d_in[1];
  const float* priors = (const float*)d_in[2];
  float* out = (float*)d_out;

  int P = in_sizes[2] / 4;          // 8732
  int B = in_sizes[0] / (P * 4);    // 128
  int g1 = (B * P + 255) / 256;
  int g2 = B * (NCLS - 1);          // 2560 tasks

  size_t need2 = (size_t)B * (NCLS - 1) * P * sizeof(float);   // ~89 MB
  size_t need1 = (size_t)B * P * sizeof(float2);               // ~18 MB

  float2* denoms = (float2*)d_ws;
  float* probs_t = (float*)d_ws;

  if (ws_size >= need2) {
    prep_k<2><<<g1, 256, 0, stream>>>(conf, denoms, probs_t, B, P);
    ssd_k<2><<<g2, 256, 0, stream>>>(loc, conf, priors, denoms, probs_t, out, B, P);
  } else if (ws_size >= need1) {
    prep_k<1><<<g1, 256, 0, stream>>>(conf, denoms, probs_t, B, P);
    ssd_k<1><<<g2, 256, 0, stream>>>(loc, conf, priors, denoms, probs_t, out, B, P);
  } else {
    ssd_k<0><<<g2, 256, 0, stream>>>(loc, conf, priors, denoms, probs_t, out, B, P);
  }
}

// Round 14
// 309.709 us; speedup vs baseline: 1.2861x; 1.2861x over previous
//
#include <hip/hip_runtime.h>
#include <cstdint>

typedef unsigned int u32;
typedef unsigned long long u64;

#define NCLS 21
#define TOPK 200
#define MAXP 8732
#define CAND 384
#define NXCD 8

// Scores: XLA:GPU(gfx950) softmax emulation — exp(x) = v_exp_f32(x*log2e),
// butterfly-tree sum. Everything else stepwise IEEE f32, no fusion.
// ALL numeric ops bit-identical to the round-13 passing kernel.
#pragma clang fp contract(off)

__device__ __forceinline__ float tri_expf(float x) {
  float t = __fmul_rn(x, 1.4426950408889634f);
  return __builtin_amdgcn_exp2f(t);               // v_exp_f32
}

__device__ __forceinline__ float butterfly_sum21(const float* e) {
  float v[32];
#pragma unroll
  for (int k = 0; k < NCLS; ++k) v[k] = e[k];
#pragma unroll
  for (int k = NCLS; k < 32; ++k) v[k] = 0.0f;
  float a[16], b[8], c4[4], d2[2];
#pragma unroll
  for (int i = 0; i < 16; ++i) a[i] = __fadd_rn(v[i], v[i + 16]);
#pragma unroll
  for (int i = 0; i < 8; ++i) b[i] = __fadd_rn(a[i], a[i + 8]);
#pragma unroll
  for (int i = 0; i < 4; ++i) c4[i] = __fadd_rn(b[i], b[i + 4]);
#pragma unroll
  for (int i = 0; i < 2; ++i) d2[i] = __fadd_rn(c4[i], c4[i + 2]);
  return __fadd_rn(d2[0], d2[1]);
}

__device__ __forceinline__ void softmax_row(const float* __restrict__ row,
                                            float* e, float& mx, float& S) {
  float xs[NCLS];
#pragma unroll
  for (int k = 0; k < NCLS; ++k) xs[k] = row[k];
  mx = xs[0];
#pragma unroll
  for (int k = 1; k < NCLS; ++k) mx = fmaxf(mx, xs[k]);
#pragma unroll
  for (int k = 0; k < NCLS; ++k) e[k] = tri_expf(__fsub_rn(xs[k], mx));
  S = butterfly_sum21(e);
}

// XCD-aware bijective task swizzle (nwg % 8 == 0 for B=128)
__device__ __forceinline__ int swz_task(int bid, int nwg) {
  if ((nwg % NXCD) == 0) return (bid % NXCD) * (nwg / NXCD) + bid / NXCD;
  return bid;
}

// ---------------- prep: per-(b,p) softmax denoms (mx, S)
__global__ __launch_bounds__(256) void prep_k(const float* __restrict__ conf,
                                              float2* __restrict__ denoms, int BP) {
  int gid = blockIdx.x * 256 + threadIdx.x;
  if (gid >= BP) return;
  float e[NCLS], mx, S;
  softmax_row(conf + (size_t)gid * NCLS, e, mx, S);
  denoms[gid] = make_float2(mx, S);
}

// ---------------- select: per-task radix top-200, writes ordered keys to ws
template<int TIER>  // 1: use denoms; 0: recompute full row
__global__ __launch_bounds__(256) void sel_k(const float* __restrict__ conf,
                                             const float2* __restrict__ denoms,
                                             u64* __restrict__ keys, int B, int P) {
  __shared__ __align__(16) u32 sc[MAXP];
  __shared__ u64 ckey[CAND];
  __shared__ u32 hist[256];
  __shared__ int srt[TOPK];
  __shared__ u32 s_prefix;
  __shared__ int s_K, s_cnt;

  const int tid = threadIdx.x;
  const int task = swz_task(blockIdx.x, gridDim.x);
  const int b = task / (NCLS - 1), cm1 = task - b * (NCLS - 1);
  const int c = cm1 + 1;

  // ---- Phase A: f32 prob bits into LDS (bit-identical to passing kernel)
  if (TIER == 1) {
    for (int p = tid; p < P; p += 256) {
      float2 d = denoms[(size_t)b * P + p];
      float cv = conf[((size_t)b * P + p) * NCLS + c];
      float v = __fdiv_rn(tri_expf(__fsub_rn(cv, d.x)), d.y);
      sc[p] = __float_as_uint(v);
    }
  } else {
    for (int p = tid; p < P; p += 256) {
      float e[NCLS], mx, S;
      softmax_row(conf + ((size_t)b * P + p) * NCLS, e, mx, S);
      sc[p] = __float_as_uint(__fdiv_rn(e[c], S));
    }
  }
  if (tid == 0) s_cnt = 0;
  __syncthreads();

  // ---- Phase B: radix-select rank-200 threshold T (exact, with ties)
  u32 prefix = 0; int K = TOPK;
  for (int pass = 0; pass < 4; ++pass) {
    int shift = 24 - 8 * pass;
    u32 known = (pass == 0) ? 0u : (0xFFFFFFFFu << (32 - 8 * pass));
    hist[tid] = 0;
    __syncthreads();
    for (int p = tid; p < P; p += 256) {
      u32 v = sc[p];
      if ((v & known) == prefix) atomicAdd(&hist[(v >> shift) & 0xFFu], 1u);
    }
    __syncthreads();
    for (int off = 1; off < 256; off <<= 1) {   // suffix sum
      u32 add = (tid + off < 256) ? hist[tid + off] : 0u;
      __syncthreads();
      hist[tid] += add;
      __syncthreads();
    }
    u32 ge = hist[tid];
    u32 gt = (tid == 255) ? 0u : hist[tid + 1];
    if (ge >= (u32)K && gt < (u32)K) { s_prefix = prefix | ((u32)tid << shift); s_K = K - (int)gt; }
    __syncthreads();
    prefix = s_prefix; K = s_K;
    __syncthreads();
  }
  const u32 T = prefix;

  // ---- Phase C: compact candidates (bits >= T)
  for (int p = tid; p < P; p += 256) {
    u32 v = sc[p];
    if (v >= T) {
      int slot = atomicAdd(&s_cnt, 1);
      if (slot < CAND)
        ckey[slot] = ((u64)v << 32) | (u64)(0xFFFFFFFFu - (u32)p);
    }
  }
  __syncthreads();
  int cnt = s_cnt; if (cnt > CAND) cnt = CAND;

  // ---- Phase D: exact rank by counting
  for (int i = tid; i < cnt; i += 256) {
    u64 k = ckey[i]; int r = 0;
    for (int j = 0; j < cnt; ++j) r += (ckey[j] > k) ? 1 : 0;
    if (r < TOPK) srt[r] = i;
  }
  __syncthreads();

  // ---- write ordered keys
  if (tid < TOPK) keys[(size_t)task * TOPK + tid] = ckey[srt[tid]];
}

// ---------------- nms: 1 wave per task; decode + greedy NMS + output
__global__ __launch_bounds__(64) void nms_k(const float* __restrict__ loc,
                                            const float* __restrict__ priors,
                                            const u64* __restrict__ keys,
                                            float* __restrict__ out, int B, int P) {
  __shared__ __align__(16) float bx[TOPK][4];
  __shared__ float vals[TOPK];
  __shared__ __align__(16) float st[TOPK * 5];

  const int lane = threadIdx.x;
  const int task = swz_task(blockIdx.x, gridDim.x);
  const int b = task / (NCLS - 1), cm1 = task - b * (NCLS - 1);

  if (cm1 == 0) {   // zero the background-class rows of this image
    float* bg = out + (size_t)b * (NCLS * TOPK * 5);
    for (int i = lane; i < TOPK * 5; i += 64) bg[i] = 0.0f;
  }

  const u64* tk = keys + (size_t)task * TOPK;
  float jx1[4], jy1[4], jx2[4], jy2[4], aj[4], myv[4];
#pragma unroll
  for (int s = 0; s < 4; ++s) {
    int j = s * 64 + lane;
    if (j < TOPK) {
      u64 key = tk[j];
      float v = __uint_as_float((u32)(key >> 32));
      int p = (int)(0xFFFFFFFFu - (u32)(key & 0xFFFFFFFFull));
      float4 lp = ((const float4*)loc)[(size_t)b * P + p];
      float4 pr = ((const float4*)priors)[p];
      // decode: bit-identical op sequence to the passing kernel
      float tx = __fmul_rn(__fmul_rn(lp.x, 0.1f), pr.z);
      float ty = __fmul_rn(__fmul_rn(lp.y, 0.1f), pr.w);
      float cx = __fadd_rn(pr.x, tx);
      float cy = __fadd_rn(pr.y, ty);
      float w = __fmul_rn(pr.z, expf(__fmul_rn(lp.z, 0.2f)));
      float h = __fmul_rn(pr.w, expf(__fmul_rn(lp.w, 0.2f)));
      float hw = __fmul_rn(w, 0.5f), hh = __fmul_rn(h, 0.5f);
      jx1[s] = __fsub_rn(cx, hw);
      jy1[s] = __fsub_rn(cy, hh);
      jx2[s] = __fadd_rn(cx, hw);
      jy2[s] = __fadd_rn(cy, hh);
      bx[j][0] = jx1[s]; bx[j][1] = jy1[s]; bx[j][2] = jx2[s]; bx[j][3] = jy2[s];
      vals[j] = v;
      myv[s] = v;
    } else {
      jx1[s] = 0.f; jy1[s] = 0.f; jx2[s] = 0.f; jy2[s] = 0.f;
      myv[s] = 1.0f;   // unused (j >= TOPK guarded below)
    }
    aj[s] = __fmul_rn(__fsub_rn(jx2[s], jx1[s]), __fsub_rn(jy2[s], jy1[s]));
  }
  __syncthreads();

  // n = first index where !(v > 0.01f), TOPK if none (== atomicMin semantics)
  int n = TOPK;
#pragma unroll
  for (int s = 3; s >= 0; --s) {
    u64 bad = __ballot((s * 64 + lane < TOPK) && !(myv[s] > 0.01f));
    if (bad) n = s * 64 + (__ffsll((long long)bad) - 1);
  }

  // greedy NMS (exact ref IoU formula, bit-identical ops), prefetched bi
  u32 keepn = 0;
  float4 bi = *(const float4*)bx[0];
  for (int i = 0; i < n; ++i) {
    float4 bnext = (i + 1 < n) ? *(const float4*)bx[i + 1] : bi;
    float ai = __fmul_rn(__fsub_rn(bi.z, bi.x), __fsub_rn(bi.w, bi.y));
    bool sup = false;
#pragma unroll
    for (int s = 0; s < 4; ++s) {
      float ww = fmaxf(__fsub_rn(fminf(bi.z, jx2[s]), fmaxf(bi.x, jx1[s])), 0.0f);
      float hh = fmaxf(__fsub_rn(fminf(bi.w, jy2[s]), fmaxf(bi.y, jy1[s])), 0.0f);
      float inter = __fmul_rn(ww, hh);
      float den = __fsub_rn(__fadd_rn(ai, aj[s]), inter);
      float iou = __fdiv_rn(inter, den);
      if (((keepn >> s) & 1u) && (iou > 0.45f)) sup = true;
    }
    if (!__any((int)sup)) { if (lane == (i & 63)) keepn |= 1u << (i >> 6); }
    bi = bnext;
  }
  u64 kw[4];
#pragma unroll
  for (int s = 0; s < 4; ++s) kw[s] = __ballot((int)((keepn >> s) & 1u));

  // compact kept rows to front, zeros elsewhere; coalesced store
  for (int i = lane; i < TOPK * 5; i += 64) st[i] = 0.0f;
  __syncthreads();
#pragma unroll
  for (int s = 0; s < 4; ++s) {
    int j = s * 64 + lane;
    if (j < TOPK && ((kw[s] >> lane) & 1ull)) {
      int pos = (int)__popcll(kw[s] & ((1ull << lane) - 1ull));
      for (int s2 = 0; s2 < s; ++s2) pos += (int)__popcll(kw[s2]);
      st[pos * 5 + 0] = vals[j];
      st[pos * 5 + 1] = bx[j][0];
      st[pos * 5 + 2] = bx[j][1];
      st[pos * 5 + 3] = bx[j][2];
      st[pos * 5 + 4] = bx[j][3];
    }
  }
  __syncthreads();
  float* op = out + (size_t)(b * NCLS + 1 + cm1) * (TOPK * 5);
  for (int i = lane; i < TOPK * 5 / 4; i += 64) ((float4*)op)[i] = ((const float4*)st)[i];
}

// ---------------- fused fallback (verified R13 TIER-0 kernel), used if ws tiny
__global__ __launch_bounds__(256) void fused_k(
    const float* __restrict__ loc, const float* __restrict__ conf,
    const float* __restrict__ priors, float* __restrict__ out, int B, int P) {
  __shared__ __align__(16) u32 sc[MAXP];
  __shared__ u64 ckey[CAND];
  __shared__ u32 hist[256];
  __shared__ int srt[TOPK];
  __shared__ float bx[TOPK][4];
  __shared__ float vals[TOPK];
  __shared__ __align__(16) float st[TOPK * 5];
  __shared__ u32 s_prefix;
  __shared__ int s_K, s_cnt, s_nv;
  __shared__ u64 s_kw[4];

  const int tid = threadIdx.x;
  const int task = blockIdx.x;
  const int b = task / (NCLS - 1), cm1 = task - b * (NCLS - 1);
  const int c = cm1 + 1;

  if (cm1 == 0) {
    float* bg = out + (size_t)b * (NCLS * TOPK * 5);
    for (int i = tid; i < TOPK * 5; i += 256) bg[i] = 0.0f;
  }
  for (int p = tid; p < P; p += 256) {
    float e[NCLS], mx, S;
    softmax_row(conf + ((size_t)b * P + p) * NCLS, e, mx, S);
    sc[p] = __float_as_uint(__fdiv_rn(e[c], S));
  }
  if (tid == 0) s_cnt = 0;
  __syncthreads();
  u32 prefix = 0; int K = TOPK;
  for (int pass = 0; pass < 4; ++pass) {
    int shift = 24 - 8 * pass;
    u32 known = (pass == 0) ? 0u : (0xFFFFFFFFu << (32 - 8 * pass));
    hist[tid] = 0;
    __syncthreads();
    for (int p = tid; p < P; p += 256) {
      u32 v = sc[p];
      if ((v & known) == prefix) atomicAdd(&hist[(v >> shift) & 0xFFu], 1u);
    }
    __syncthreads();
    for (int off = 1; off < 256; off <<= 1) {
      u32 add = (tid + off < 256) ? hist[tid + off] : 0u;
      __syncthreads();
      hist[tid] += add;
      __syncthreads();
    }
    u32 ge = hist[tid];
    u32 gt = (tid == 255) ? 0u : hist[tid + 1];
    if (ge >= (u32)K && gt < (u32)K) { s_prefix = prefix | ((u32)tid << shift); s_K = K - (int)gt; }
    __syncthreads();
    prefix = s_prefix; K = s_K;
    __syncthreads();
  }
  const u32 T = prefix;
  for (int p = tid; p < P; p += 256) {
    u32 v = sc[p];
    if (v >= T) {
      int slot = atomicAdd(&s_cnt, 1);
      if (slot < CAND) ckey[slot] = ((u64)v << 32) | (u64)(0xFFFFFFFFu - (u32)p);
    }
  }
  __syncthreads();
  int cnt = s_cnt; if (cnt > CAND) cnt = CAND;
  for (int i = tid; i < cnt; i += 256) {
    u64 k = ckey[i]; int r = 0;
    for (int j = 0; j < cnt; ++j) r += (ckey[j] > k) ? 1 : 0;
    if (r < TOPK) srt[r] = i;
  }
  if (tid == 0) s_nv = TOPK;
  __syncthreads();
  if (tid < TOPK) {
    u64 key = ckey[srt[tid]];
    float v = __uint_as_float((u32)(key >> 32));
    int p = (int)(0xFFFFFFFFu - (u32)(key & 0xFFFFFFFFull));
    float4 lp = ((const float4*)loc)[(size_t)b * P + p];
    float4 pr = ((const float4*)priors)[p];
    float tx = __fmul_rn(__fmul_rn(lp.x, 0.1f), pr.z);
    float ty = __fmul_rn(__fmul_rn(lp.y, 0.1f), pr.w);
    float cx = __fadd_rn(pr.x, tx);
    float cy = __fadd_rn(pr.y, ty);
    float w = __fmul_rn(pr.z, expf(__fmul_rn(lp.z, 0.2f)));
    float h = __fmul_rn(pr.w, expf(__fmul_rn(lp.w, 0.2f)));
    float hw = __fmul_rn(w, 0.5f), hh = __fmul_rn(h, 0.5f);
    bx[tid][0] = __fsub_rn(cx, hw);
    bx[tid][1] = __fsub_rn(cy, hh);
    bx[tid][2] = __fadd_rn(cx, hw);
    bx[tid][3] = __fadd_rn(cy, hh);
    vals[tid] = v;
    if (!(v > 0.01f)) atomicMin(&s_nv, tid);
  }
  __syncthreads();
  if (tid < 64) {
    int lane = tid;
    float jx1[4], jy1[4], jx2[4], jy2[4], aj[4];
#pragma unroll
    for (int s = 0; s < 4; ++s) {
      int j = s * 64 + lane;
      if (j < TOPK) { jx1[s]=bx[j][0]; jy1[s]=bx[j][1]; jx2[s]=bx[j][2]; jy2[s]=bx[j][3]; }
      else { jx1[s]=0.f; jy1[s]=0.f; jx2[s]=0.f; jy2[s]=0.f; }
      aj[s] = __fmul_rn(__fsub_rn(jx2[s], jx1[s]), __fsub_rn(jy2[s], jy1[s]));
    }
    u32 keepn = 0;
    int n = s_nv;
    for (int i = 0; i < n; ++i) {
      float ix1 = bx[i][0], iy1 = bx[i][1], ix2 = bx[i][2], iy2 = bx[i][3];
      float ai = __fmul_rn(__fsub_rn(ix2, ix1), __fsub_rn(iy2, iy1));
      bool sup = false;
#pragma unroll
      for (int s = 0; s < 4; ++s) {
        float ww = fmaxf(__fsub_rn(fminf(ix2, jx2[s]), fmaxf(ix1, jx1[s])), 0.0f);
        float hh = fmaxf(__fsub_rn(fminf(iy2, jy2[s]), fmaxf(iy1, jy1[s])), 0.0f);
        float inter = __fmul_rn(ww, hh);
        float den = __fsub_rn(__fadd_rn(ai, aj[s]), inter);
        float iou = __fdiv_rn(inter, den);
        if (((keepn >> s) & 1u) && (iou > 0.45f)) sup = true;
      }
      if (!__any((int)sup)) { if (lane == (i & 63)) keepn |= 1u << (i >> 6); }
    }
    u64 w0 = __ballot((int)(keepn & 1u));
    u64 w1 = __ballot((int)((keepn >> 1) & 1u));
    u64 w2 = __ballot((int)((keepn >> 2) & 1u));
    u64 w3 = __ballot((int)((keepn >> 3) & 1u));
    if (lane == 0) { s_kw[0]=w0; s_kw[1]=w1; s_kw[2]=w2; s_kw[3]=w3; }
  }
  __syncthreads();
  for (int i = tid; i < TOPK * 5; i += 256) st[i] = 0.0f;
  __syncthreads();
  if (tid < TOPK) {
    int w = tid >> 6, bit = tid & 63;
    u64 kwv = s_kw[w];
    if ((kwv >> bit) & 1ull) {
      int pos = (int)__popcll(kwv & ((1ull << bit) - 1ull));
      for (int w2 = 0; w2 < w; ++w2) pos += (int)__popcll(s_kw[w2]);
      st[pos*5+0] = vals[tid];
      st[pos*5+1] = bx[tid][0];
      st[pos*5+2] = bx[tid][1];
      st[pos*5+3] = bx[tid][2];
      st[pos*5+4] = bx[tid][3];
    }
  }
  __syncthreads();
  float* op = out + (size_t)(b * NCLS + 1 + cm1) * (TOPK * 5);
  if (tid < TOPK * 5 / 4) ((float4*)op)[tid] = ((const float4*)st)[tid];
}

extern "C" void kernel_launch(void* const* d_in, const int* in_sizes, int n_in,
                              void* d_out, int out_size, void* d_ws, size_t ws_size,
                              hipStream_t stream) {
  const float* loc    = (const float*)d_in[0];
  const float* conf   = (const float*)d_in[1];
  const float* priors = (const float*)d_in[2];
  float* out = (float*)d_out;

  int P = in_sizes[2] / 4;              // 8732
  int B = in_sizes[0] / (P * 4);        // 128
  int tasks = B * (NCLS - 1);           // 2560
  int BP = B * P;

  size_t keysB = (size_t)tasks * TOPK * sizeof(u64);     // ~4.1 MB
  size_t denB  = (size_t)BP * sizeof(float2);            // ~8.9 MB

  if (ws_size >= denB + keysB) {
    float2* denoms = (float2*)d_ws;
    u64* keys = (u64*)((char*)d_ws + denB);
    prep_k<<<(BP + 255) / 256, 256, 0, stream>>>(conf, denoms, BP);
    sel_k<1><<<tasks, 256, 0, stream>>>(conf, denoms, keys, B, P);
    nms_k<<<tasks, 64, 0, stream>>>(loc, priors, keys, out, B, P);
  } else if (ws_size >= keysB) {
    u64* keys = (u64*)d_ws;
    sel_k<0><<<tasks, 256, 0, stream>>>(conf, (const float2*)nullptr, keys, B, P);
    nms_k<<<tasks, 64, 0, stream>>>(loc, priors, keys, out, B, P);
  } else {
    fused_k<<<tasks, 256, 0, stream>>>(loc, conf, priors, out, B, P);
  }
}